// Round 8
// baseline (1426.414 us; speedup 1.0000x reference)
//
#include <hip/hip_runtime.h>

typedef __bf16 bf16_t;
typedef __bf16 bf16x8 __attribute__((ext_vector_type(8)));
typedef float f32x4 __attribute__((ext_vector_type(4)));

#define TSEQ 30
#define ISZ  100
#define HSZ  256
#define NB   5120        // LSTM batch
#define BATCH 512
#define G4   1024        // 4*H
#define XP   128         // padded x feature size
#define KP   384         // padded K
#define TILE 320         // batch cols per block
#define NBGRP 16
#define NMSUB 8

__device__ __forceinline__ float fsig(float x)  { return 1.0f / (1.0f + __expf(-x)); }
__device__ __forceinline__ float ftanh(float x) { return 2.0f / (1.0f + __expf(-2.0f * x)) - 1.0f; }

// ---- prep: weights -> MFMA-fragment layout, fold biases ------------------
// Wf[d][mf 0..63][ks 0..11][lane 0..63][e 0..7]; gate row r = h*4+gate
__global__ void prep_weights(const float* __restrict__ Wih_f, const float* __restrict__ Whh_f,
                             const float* __restrict__ bih_f, const float* __restrict__ bhh_f,
                             const float* __restrict__ Wih_b, const float* __restrict__ Whh_b,
                             const float* __restrict__ bih_b, const float* __restrict__ bhh_b,
                             bf16_t* __restrict__ Wf, float* __restrict__ bias)
{
    int idx = blockIdx.x * 256 + threadIdx.x;          // over 2*1024*384
    if (idx >= 2 * G4 * KP) return;
    int d = idx / (G4 * KP);
    int r = (idx / KP) % G4;
    int k = idx % KP;
    int h = r >> 2, gate = r & 3;
    int grow = gate * HSZ + h;
    const float* Wih = d ? Wih_b : Wih_f;
    const float* Whh = d ? Whh_b : Whh_f;
    float v;
    if (k < ISZ)       v = Wih[grow * ISZ + k];
    else if (k < XP)   v = 0.0f;
    else               v = Whh[grow * HSZ + (k - XP)];
    int mf = r >> 4, lr = r & 15;
    int ks = k >> 5, lq = (k >> 3) & 3, e = k & 7;
    size_t o = ((((size_t)d * 64 + mf) * 12 + ks) * 64 + lq * 16 + lr) * 8 + e;
    Wf[o] = (bf16_t)v;
    if (k == 0) {
        const float* bih = d ? bih_b : bih_f;
        const float* bhh = d ? bhh_b : bhh_f;
        bias[d * G4 + r] = bih[grow] + bhh[grow];
    }
}

// ---- prep: x -> B-fragment layout per (bgrp, t) --------------------------
// xBf[bgrp][t][nblk 0..19][ks 0..3][lane][e]: col=bgrp*320+nblk*16+lr, k=ks*32+lq*8+e
__global__ void prep_x(const float* __restrict__ x, bf16_t* __restrict__ xBf)
{
    int idx = blockIdx.x * 256 + threadIdx.x;          // over 16*30*20*4*512 = 19,660,800
    if (idx >= NBGRP * TSEQ * 20 * 4 * 512) return;
    int e    = idx & 7;
    int lane = (idx >> 3) & 63;
    int ks   = (idx >> 9) & 3;
    int r    = idx >> 11;                              // (bgrp*30 + t)*20 + nblk
    int nblk = r % 20; r /= 20;
    int t    = r % TSEQ;
    int bgrp = r / TSEQ;
    int lr = lane & 15, lq = lane >> 4;
    int n = bgrp * TILE + nblk * 16 + lr;
    int k = ks * 32 + lq * 8 + e;
    float v = (k < ISZ) ? x[(size_t)n * (TSEQ * ISZ) + t * ISZ + k] : 0.0f;
    xBf[idx] = (bf16_t)v;
}

// ---- prep: h0 -> bf16 ping buffer ----------------------------------------
__global__ void prep_state(const float* __restrict__ h0, bf16_t* __restrict__ hb0)
{
    int idx = blockIdx.x * 256 + threadIdx.x;          // over 2*5120*256
    if (idx >= 2 * NB * HSZ) return;
    hb0[idx] = (bf16_t)h0[idx];
}

// ---- prep: transpose W1 for coalesced head ------------------------------
__global__ void prep_w1t(const float* __restrict__ W1, float* __restrict__ W1T)
{
    int idx = blockIdx.x * 256 + threadIdx.x;          // over 2560*64
    if (idx >= 2560 * 64) return;
    int k = idx / 64, j = idx % 64;
    W1T[k * 64 + j] = W1[j * 2560 + k];
}

// ---- device-scope grid barrier (256 co-resident blocks, monotonic count) --
__device__ __forceinline__ void grid_barrier(unsigned* bar, unsigned target)
{
    __syncthreads();
    if (threadIdx.x == 0) {
        __threadfence();                               // release: drain + wb
        __hip_atomic_fetch_add(bar, 1u, __ATOMIC_RELEASE, __HIP_MEMORY_SCOPE_AGENT);
        while (__hip_atomic_load(bar, __ATOMIC_ACQUIRE, __HIP_MEMORY_SCOPE_AGENT) < target)
            __builtin_amdgcn_s_sleep(1);
        __threadfence();                               // acquire: inv L1/L2
    }
    __syncthreads();
}

// ---- persistent LSTM, M-split + W-in-LDS ---------------------------------
// 256 blocks x 512 thr, 1 block/CU (96KB+ LDS). bid = msub*32 + dir*16 + bgrp
// (=> bid%8 = bgrp&7: h-exchange group shares an XCD under round-robin).
// Block: M-slice 128 gate rows (32 h), 320 cols, W-slice LDS-resident (96KB,
// staged ONCE -> zero per-step global W traffic; r2-r7: streamed W missed L2
// ~50% no matter what). h ping-pongs via global bf16 + 1 barrier/step.
__global__ __launch_bounds__(512, 1)
void lstm_persist(const bf16_t* __restrict__ Wf, const float* __restrict__ bias,
                  const bf16_t* __restrict__ xBf, const float* __restrict__ c0,
                  bf16_t* __restrict__ hb0, bf16_t* __restrict__ hb1,
                  unsigned* __restrict__ bar)
{
    __shared__ __align__(16) bf16_t wL[8 * 12 * 512];  // 96KB W slice
    __shared__ __align__(16) float  cL[TILE * 32];     // 40KB c0 staging

    const int bid  = blockIdx.x;
    const int msub = bid >> 5;
    const int dir  = (bid >> 4) & 1;
    const int bgrp = bid & 15;
    const int tid  = threadIdx.x;
    const int lane = tid & 63;
    const int mw   = (tid >> 6) >> 2;                  // 0..1
    const int nw   = (tid >> 6) & 3;                   // 0..3
    const int lr   = lane & 15;
    const int lq   = lane >> 4;

    // --- stage W slice (once) + c0 slice ---
    {
        const uint4* wsrc = (const uint4*)(Wf + ((size_t)dir * 64 + msub * 8) * 12 * 512);
        uint4* wdst = (uint4*)wL;
        for (int i = tid; i < 6144; i += 512) wdst[i] = wsrc[i];
        const float* csrc = c0 + ((size_t)dir * NB + bgrp * TILE) * HSZ + msub * 32;
        for (int i = tid; i < 2560; i += 512) {
            int n = i >> 3, hq = i & 7;
            *(float4*)(cL + n * 32 + hq * 4) = *(const float4*)(csrc + (size_t)n * HSZ + hq * 4);
        }
    }
    __syncthreads();

    // --- per-lane state: c, bias quads ---
    float cst[4][5];
    float4 bq[4];
#pragma unroll
    for (int mf = 0; mf < 4; ++mf) {
        int hhl = mw * 16 + mf * 4 + lq;
        bq[mf] = *(const float4*)(bias + dir * G4 + (msub * 32 + hhl) * 4);
#pragma unroll
        for (int nf = 0; nf < 5; ++nf)
            cst[mf][nf] = cL[(nw * 80 + nf * 16 + lr) * 32 + hhl];
    }

    const bf16_t* xgb = xBf + (size_t)bgrp * TSEQ * 20 * 4 * 512;

#pragma unroll 1
    for (int t = 0; t < TSEQ; ++t) {
        const bf16_t* hrd = (t & 1) ? hb1 : hb0;
        bf16_t*       hwr = (t & 1) ? hb0 : hb1;
        const int tx = dir ? (TSEQ - 1 - t) : t;
        const bf16_t* xb = xgb + (size_t)tx * 20 * 4 * 512;
        const bf16_t* hbase = hrd + (size_t)dir * NB * HSZ + (size_t)bgrp * TILE * HSZ;

        f32x4 acc[4][5] = {};
#pragma unroll
        for (int ks = 0; ks < 12; ++ks) {
            bf16x8 b[5];
#pragma unroll
            for (int nf = 0; nf < 5; ++nf) {
                int nblk = nw * 5 + nf;
                if (ks < 4)
                    b[nf] = *(const bf16x8*)(xb + ((size_t)nblk * 4 + ks) * 512 + lane * 8);
                else
                    b[nf] = *(const bf16x8*)(hbase + (size_t)(nblk * 16 + lr) * HSZ + (ks - 4) * 32 + lq * 8);
            }
            bf16x8 a[4];
#pragma unroll
            for (int m = 0; m < 4; ++m)
                a[m] = *(const bf16x8*)(wL + (((mw * 4 + m) * 12 + ks) * 512 + lane * 8));
#pragma unroll
            for (int m = 0; m < 4; ++m)
#pragma unroll
                for (int nf = 0; nf < 5; ++nf)
                    acc[m][nf] = __builtin_amdgcn_mfma_f32_16x16x32_bf16(a[m], b[nf], acc[m][nf], 0, 0, 0);
        }

        // --- gates + state; h -> hwr (bf16, device-visible after barrier) ---
        bf16_t* hwbase = hwr + (size_t)dir * NB * HSZ + (size_t)bgrp * TILE * HSZ;
        int hh = msub * 32 + mw * 16 + lq;             // + mf*4 below
#pragma unroll
        for (int mf = 0; mf < 4; ++mf) {
            float4 bb = bq[mf];
#pragma unroll
            for (int nf = 0; nf < 5; ++nf) {
                int n = nw * 80 + nf * 16 + lr;
                f32x4 g = acc[mf][nf];
                float gi = fsig(g[0] + bb.x);
                float gf = fsig(g[1] + bb.y);
                float gz = ftanh(g[2] + bb.z);
                float go = fsig(g[3] + bb.w);
                float cn = gf * cst[mf][nf] + gi * gz;
                cst[mf][nf] = cn;
                hwbase[(size_t)n * HSZ + hh + mf * 4] = (bf16_t)(go * ftanh(cn));
            }
        }

        if (t < TSEQ - 1) grid_barrier(bar, 256u * (unsigned)(t + 1));
    }
}

// ---- head: x_fea assembly + Linear(2560,64) + Linear(64,5) + softmax ----
__global__ __launch_bounds__(256)
void head_kernel(const bf16_t* __restrict__ hfin, const float* __restrict__ W1T,
                 const float* __restrict__ b1, const float* __restrict__ W2,
                 const float* __restrict__ b2, float* __restrict__ out)
{
    __shared__ float flat_s[2560];
    __shared__ float partial[4][64];
    __shared__ float zs[64];
    __shared__ float ls[5];
    __shared__ float es[5];
    int b = blockIdx.x, tid = threadIdx.x;
    const bf16_t* hF = hfin;
    const bf16_t* hB = hfin + (size_t)NB * HSZ;
    float* xfea = out + BATCH * 5 + (size_t)b * 2560;

    for (int j = tid; j < 2560; j += 256) {
        int s = j >> 8, c = j & 255;
        int n = b * 10 + s;
        float v = (c < 128) ? (float)hF[(size_t)n * HSZ + c] : (float)hB[(size_t)n * HSZ + c];
        flat_s[j] = v;
        xfea[j] = v;
    }
    __syncthreads();
    int j = tid & 63, q = tid >> 6;
    float sum = 0.0f;
    for (int k = q * 640; k < (q + 1) * 640; ++k) sum += flat_s[k] * W1T[k * 64 + j];
    partial[q][j] = sum;
    __syncthreads();
    if (tid < 64) zs[tid] = partial[0][tid] + partial[1][tid] + partial[2][tid] + partial[3][tid] + b1[tid];
    __syncthreads();
    if (tid < 5) {
        float l = b2[tid];
        for (int k = 0; k < 64; ++k) l += zs[k] * W2[tid * 64 + k];
        ls[tid] = l;
    }
    __syncthreads();
    if (tid < 5) {
        float m = ls[0];
        for (int k = 1; k < 5; ++k) m = fmaxf(m, ls[k]);
        es[tid] = __expf(ls[tid] - m);
    }
    __syncthreads();
    if (tid < 5) {
        float s5 = es[0] + es[1] + es[2] + es[3] + es[4];
        out[b * 5 + tid] = es[tid] / s5;
    }
}

extern "C" void kernel_launch(void* const* d_in, const int* in_sizes, int n_in,
                              void* d_out, int out_size, void* d_ws, size_t ws_size,
                              hipStream_t stream) {
    const float* x     = (const float*)d_in[0];
    const float* h0    = (const float*)d_in[1];
    const float* c0    = (const float*)d_in[2];
    const float* Wih_f = (const float*)d_in[3];
    const float* Whh_f = (const float*)d_in[4];
    const float* bih_f = (const float*)d_in[5];
    const float* bhh_f = (const float*)d_in[6];
    const float* Wih_b = (const float*)d_in[7];
    const float* Whh_b = (const float*)d_in[8];
    const float* bih_b = (const float*)d_in[9];
    const float* bhh_b = (const float*)d_in[10];
    const float* W1    = (const float*)d_in[11];
    const float* b1    = (const float*)d_in[12];
    const float* W2    = (const float*)d_in[13];
    const float* b2    = (const float*)d_in[14];
    float* out = (float*)d_out;

    uintptr_t ws = (uintptr_t)d_ws;
    bf16_t*   Wf   = (bf16_t*)(ws);                    // 1,572,864
    float*    bias = (float*)(ws + 1572864);           // 8,192
    bf16_t*   xBf  = (bf16_t*)(ws + 1581056);          // 39,321,600
    bf16_t*   hb0  = (bf16_t*)(ws + 40902656);         // 5,242,880
    bf16_t*   hb1  = (bf16_t*)(ws + 46145536);         // 5,242,880
    float*    W1T  = (float*)(ws + 51388416);          // 655,360
    unsigned* bar  = (unsigned*)(ws + 52043776);       // 64

    hipMemsetAsync((void*)bar, 0, 64, stream);

    prep_weights<<<(2 * G4 * KP + 255) / 256, 256, 0, stream>>>(
        Wih_f, Whh_f, bih_f, bhh_f, Wih_b, Whh_b, bih_b, bhh_b, Wf, bias);
    prep_x<<<(NBGRP * TSEQ * 20 * 4 * 512 + 255) / 256, 256, 0, stream>>>(x, xBf);
    prep_state<<<(2 * NB * HSZ + 255) / 256, 256, 0, stream>>>(h0, hb0);
    prep_w1t<<<(2560 * 64 + 255) / 256, 256, 0, stream>>>(W1, W1T);

    lstm_persist<<<256, 512, 0, stream>>>(Wf, bias, xBf, c0, hb0, hb1, bar);
    head_kernel<<<BATCH, 256, 0, stream>>>(hb0, W1T, b1, W2, b2, out);
}

// Round 9
// 986.355 us; speedup vs baseline: 1.4461x; 1.4461x over previous
//
#include <hip/hip_runtime.h>

typedef __bf16 bf16_t;
typedef __bf16 bf16x8 __attribute__((ext_vector_type(8)));
typedef float f32x4 __attribute__((ext_vector_type(4)));

#define TSEQ 30
#define ISZ  100
#define HSZ  256
#define NB   5120        // LSTM batch
#define BATCH 512
#define G4   1024        // 4*H
#define TILE 320         // batch cols per block
#define NBGRP 16
#define CH   10240       // elements per K=32 chunk panel: 20 nblk * 512
#define SLABX (4 * CH)   // x slab per (bgrp,t): K=128
#define SLABH (8 * CH)   // h slab per (dir,bgrp): K=256

__device__ __forceinline__ float fsig(float x)  { return 1.0f / (1.0f + __expf(-x)); }
__device__ __forceinline__ float ftanh(float x) { return 2.0f / (1.0f + __expf(-2.0f * x)) - 1.0f; }

// ---- prep: weights -> MFMA-fragment layout, fold biases ------------------
// Wf[d][mf 0..63][ks 0..11][lane 0..63][e 0..7]; gate row r = h*4+gate
__global__ void prep_weights(const float* __restrict__ Wih_f, const float* __restrict__ Whh_f,
                             const float* __restrict__ bih_f, const float* __restrict__ bhh_f,
                             const float* __restrict__ Wih_b, const float* __restrict__ Whh_b,
                             const float* __restrict__ bih_b, const float* __restrict__ bhh_b,
                             bf16_t* __restrict__ Wf, float* __restrict__ bias)
{
    int idx = blockIdx.x * 256 + threadIdx.x;          // over 2*1024*384
    if (idx >= 2 * G4 * 384) return;
    int d = idx / (G4 * 384);
    int r = (idx / 384) % G4;
    int k = idx % 384;
    int h = r >> 2, gate = r & 3;
    int grow = gate * HSZ + h;
    const float* Wih = d ? Wih_b : Wih_f;
    const float* Whh = d ? Whh_b : Whh_f;
    float v;
    if (k < ISZ)       v = Wih[grow * ISZ + k];
    else if (k < 128)  v = 0.0f;
    else               v = Whh[grow * HSZ + (k - 128)];
    int mf = r >> 4, lr = r & 15;
    int ks = k >> 5, lq = (k >> 3) & 3, e = k & 7;
    size_t o = ((((size_t)d * 64 + mf) * 12 + ks) * 64 + lq * 16 + lr) * 8 + e;
    Wf[o] = (bf16_t)v;
    if (k == 0) {
        const float* bih = d ? bih_b : bih_f;
        const float* bhh = d ? bhh_b : bhh_f;
        bias[d * G4 + r] = bih[grow] + bhh[grow];
    }
}

// ---- prep: x -> fragment layout, chunk-contiguous ------------------------
// xBf[bgrp][t][ks 0..3][nblk 0..19][lane][e]
__global__ void prep_x(const float* __restrict__ x, bf16_t* __restrict__ xBf)
{
    int idx = blockIdx.x * 256 + threadIdx.x;          // over 16*30*4*20*512
    if (idx >= NBGRP * TSEQ * SLABX) return;
    int e    = idx & 7;
    int lane = (idx >> 3) & 63;
    int i2   = idx >> 9;
    int nblk = i2 % 20; i2 /= 20;
    int ks   = i2 & 3;  i2 >>= 2;
    int t    = i2 % TSEQ;
    int bgrp = i2 / TSEQ;
    int n = bgrp * TILE + nblk * 16 + (lane & 15);
    int k = ks * 32 + (lane >> 4) * 8 + e;
    float v = (k < ISZ) ? x[(size_t)n * (TSEQ * ISZ) + t * ISZ + k] : 0.0f;
    xBf[idx] = (bf16_t)v;
}

// ---- prep: h0 -> fragment layout ping buffer -----------------------------
// hA[dir][bgrp][ksh 0..7][nblk 0..19][lane][e]
__global__ void prep_state(const float* __restrict__ h0, bf16_t* __restrict__ hA)
{
    int idx = blockIdx.x * 256 + threadIdx.x;          // over 2*16*8*20*512
    if (idx >= 2 * NBGRP * SLABH) return;
    int e    = idx & 7;
    int lane = (idx >> 3) & 63;
    int i2   = idx >> 9;
    int nblk = i2 % 20; i2 /= 20;
    int ksh  = i2 & 7;  i2 >>= 3;
    int bgrp = i2 & 15;
    int dir  = i2 >> 4;
    int col = bgrp * TILE + nblk * 16 + (lane & 15);
    int hid = ksh * 32 + (lane >> 4) * 8 + e;
    hA[idx] = (bf16_t)h0[((size_t)dir * NB + col) * HSZ + hid];
}

// ---- prep: transpose W1 for coalesced head ------------------------------
__global__ void prep_w1t(const float* __restrict__ W1, float* __restrict__ W1T)
{
    int idx = blockIdx.x * 256 + threadIdx.x;          // over 2560*64
    if (idx >= 2560 * 64) return;
    int k = idx / 64, j = idx % 64;
    W1T[k * 64 + j] = W1[j * 2560 + k];
}

// ---- 8-way group barrier (per (dir,bgrp), monotonic count) ---------------
__device__ __forceinline__ void group_barrier(unsigned* bar, unsigned target)
{
    __syncthreads();                                   // all waves' stores retired (waitcnt before s_barrier)
    if (threadIdx.x == 0) {
        __threadfence();
        __hip_atomic_fetch_add(bar, 1u, __ATOMIC_RELEASE, __HIP_MEMORY_SCOPE_AGENT);
        while (__hip_atomic_load(bar, __ATOMIC_ACQUIRE, __HIP_MEMORY_SCOPE_AGENT) < target)
            __builtin_amdgcn_s_sleep(1);
        __threadfence();
    }
    __syncthreads();
}

// ---- persistent LSTM: M-split + W-in-LDS + B via double-buffered LDS chunks
// 256 blocks x 512 thr, 1 block/CU. bid = msub*32 + dir*16 + bgrp.
// Sync group = the 8 msub-blocks sharing (dir,bgrp) (all on one XCD under
// round-robin; r8 verified h-exchange stays XCD-L2-local, FETCH 44MB).
// r8 lesson: per-wave gather loads of B from global = latency wall (40µs/step);
// now B is staged as linear 20KB chunk copies overlapped with MFMA.
__global__ __launch_bounds__(512, 1)
void lstm_persist(const bf16_t* __restrict__ Wf, const float* __restrict__ bias,
                  const bf16_t* __restrict__ xBf, const float* __restrict__ c0,
                  bf16_t* __restrict__ hA, bf16_t* __restrict__ hB,
                  bf16_t* __restrict__ hfin, unsigned* __restrict__ bar)
{
    __shared__ __align__(16) bf16_t wL[8 * 12 * 512];  // 96KB W slice
    __shared__ __align__(16) bf16_t chk[2][CH];        // 2 x 20KB act chunks (aliases c0 staging)

    const int bid  = blockIdx.x;
    const int msub = bid >> 5;
    const int dir  = (bid >> 4) & 1;
    const int bgrp = bid & 15;
    const int tid  = threadIdx.x;
    const int lane = tid & 63;
    const int mw   = (tid >> 6) >> 2;                  // 0..1
    const int nw   = (tid >> 6) & 3;                   // 0..3
    const int lr   = lane & 15;
    const int lq   = lane >> 4;

    // --- stage W slice (once) ---
    {
        const uint4* wsrc = (const uint4*)(Wf + ((size_t)dir * 64 + msub * 8) * 12 * 512);
        uint4* wdst = (uint4*)wL;
        for (int i = tid; i < 6144; i += 512) wdst[i] = wsrc[i];
    }
    // --- c0 -> LDS (coalesced), aliasing chunk buffers ---
    float* cL = (float*)chk;                           // 40KB, used only before main loop
    {
        const float* csrc = c0 + ((size_t)dir * NB + bgrp * TILE) * HSZ + msub * 32;
        for (int i = tid; i < 2560; i += 512) {
            int n = i >> 3, hq = i & 7;
            *(float4*)(cL + n * 32 + hq * 4) = *(const float4*)(csrc + (size_t)n * HSZ + hq * 4);
        }
    }
    __syncthreads();
    float cst[4][5];
    float4 bq[4];
#pragma unroll
    for (int mf = 0; mf < 4; ++mf) {
        int hhl = mw * 16 + mf * 4 + lq;
        bq[mf] = *(const float4*)(bias + dir * G4 + (msub * 32 + hhl) * 4);
#pragma unroll
        for (int nf = 0; nf < 5; ++nf)
            cst[mf][nf] = cL[(nw * 80 + nf * 16 + lr) * 32 + hhl];
    }
    __syncthreads();                                   // cL reads done; chunks reusable

    unsigned* mybar = bar + (dir * NBGRP + bgrp) * 32;

#pragma unroll 1
    for (int t = 0; t < TSEQ; ++t) {
        const bf16_t* hs = (t & 1) ? hB : hA;
        bf16_t*       hw = (t & 1) ? hA : hB;
        const int tx = dir ? (TSEQ - 1 - t) : t;
        const bf16_t* xs  = xBf + (size_t)(bgrp * TSEQ + tx) * SLABX;
        const bf16_t* hsl = hs + (size_t)(dir * NBGRP + bgrp) * SLABH;

        // prologue: stage chunk 0 (x ks=0)
        {
            const uint4* src = (const uint4*)xs;
            uint4* dst = (uint4*)chk[0];
            for (int i = tid; i < 1280; i += 512) dst[i] = src[i];
        }
        __syncthreads();

        f32x4 acc[4][5] = {};
#pragma unroll
        for (int c = 0; c < 12; ++c) {
            const int cur = c & 1;
            if (c < 11) {                              // stage next chunk into other buffer
                const uint4* src = (c + 1 < 4)
                    ? (const uint4*)(xs  + (size_t)(c + 1) * CH)
                    : (const uint4*)(hsl + (size_t)(c - 3) * CH);
                uint4* dst = (uint4*)chk[cur ^ 1];
                for (int i = tid; i < 1280; i += 512) dst[i] = src[i];
            }
            bf16x8 b[5];
#pragma unroll
            for (int nf = 0; nf < 5; ++nf)
                b[nf] = *(const bf16x8*)(chk[cur] + (nw * 5 + nf) * 512 + lane * 8);
            bf16x8 a[4];
#pragma unroll
            for (int m = 0; m < 4; ++m)
                a[m] = *(const bf16x8*)(wL + ((mw * 4 + m) * 12 + c) * 512 + lane * 8);
#pragma unroll
            for (int m = 0; m < 4; ++m)
#pragma unroll
                for (int nf = 0; nf < 5; ++nf)
                    acc[m][nf] = __builtin_amdgcn_mfma_f32_16x16x32_bf16(a[m], b[nf], acc[m][nf], 0, 0, 0);
            __syncthreads();
        }

        // --- gates + state; h -> hw fragment layout (or hfin plain at t=29) ---
        bf16_t* hwsl = hw + (size_t)(dir * NBGRP + bgrp) * SLABH;
#pragma unroll
        for (int m = 0; m < 4; ++m) {
            float4 bb = bq[m];
#pragma unroll
            for (int nf = 0; nf < 5; ++nf) {
                f32x4 g = acc[m][nf];
                float gi = fsig(g[0] + bb.x);
                float gf = fsig(g[1] + bb.y);
                float gz = ftanh(g[2] + bb.z);
                float go = fsig(g[3] + bb.w);
                float cn = gf * cst[m][nf] + gi * gz;
                cst[m][nf] = cn;
                float hn = go * ftanh(cn);
                if (t < TSEQ - 1) {
                    int hl = mw * 16 + m * 4 + lq;     // local hid within msub's 32
                    int off = (msub * 20 + nw * 5 + nf) * 512 + ((hl >> 3) * 16 + lr) * 8 + (hl & 7);
                    hwsl[off] = (bf16_t)hn;
                } else {
                    int col = bgrp * TILE + nw * 80 + nf * 16 + lr;
                    int hid = msub * 32 + mw * 16 + m * 4 + lq;
                    hfin[((size_t)dir * NB + col) * HSZ + hid] = (bf16_t)hn;
                }
            }
        }

        if (t < TSEQ - 1) group_barrier(mybar, 8u * (unsigned)(t + 1));
    }
}

// ---- head: x_fea assembly + Linear(2560,64) + Linear(64,5) + softmax ----
__global__ __launch_bounds__(256)
void head_kernel(const bf16_t* __restrict__ hfin, const float* __restrict__ W1T,
                 const float* __restrict__ b1, const float* __restrict__ W2,
                 const float* __restrict__ b2, float* __restrict__ out)
{
    __shared__ float flat_s[2560];
    __shared__ float partial[4][64];
    __shared__ float zs[64];
    __shared__ float ls[5];
    __shared__ float es[5];
    int b = blockIdx.x, tid = threadIdx.x;
    const bf16_t* hF = hfin;
    const bf16_t* hB = hfin + (size_t)NB * HSZ;
    float* xfea = out + BATCH * 5 + (size_t)b * 2560;

    for (int j = tid; j < 2560; j += 256) {
        int s = j >> 8, c = j & 255;
        int n = b * 10 + s;
        float v = (c < 128) ? (float)hF[(size_t)n * HSZ + c] : (float)hB[(size_t)n * HSZ + c];
        flat_s[j] = v;
        xfea[j] = v;
    }
    __syncthreads();
    int j = tid & 63, q = tid >> 6;
    float sum = 0.0f;
    for (int k = q * 640; k < (q + 1) * 640; ++k) sum += flat_s[k] * W1T[k * 64 + j];
    partial[q][j] = sum;
    __syncthreads();
    if (tid < 64) zs[tid] = partial[0][tid] + partial[1][tid] + partial[2][tid] + partial[3][tid] + b1[tid];
    __syncthreads();
    if (tid < 5) {
        float l = b2[tid];
        for (int k = 0; k < 64; ++k) l += zs[k] * W2[tid * 64 + k];
        ls[tid] = l;
    }
    __syncthreads();
    if (tid < 5) {
        float m = ls[0];
        for (int k = 1; k < 5; ++k) m = fmaxf(m, ls[k]);
        es[tid] = __expf(ls[tid] - m);
    }
    __syncthreads();
    if (tid < 5) {
        float s5 = es[0] + es[1] + es[2] + es[3] + es[4];
        out[b * 5 + tid] = es[tid] / s5;
    }
}

extern "C" void kernel_launch(void* const* d_in, const int* in_sizes, int n_in,
                              void* d_out, int out_size, void* d_ws, size_t ws_size,
                              hipStream_t stream) {
    const float* x     = (const float*)d_in[0];
    const float* h0    = (const float*)d_in[1];
    const float* c0    = (const float*)d_in[2];
    const float* Wih_f = (const float*)d_in[3];
    const float* Whh_f = (const float*)d_in[4];
    const float* bih_f = (const float*)d_in[5];
    const float* bhh_f = (const float*)d_in[6];
    const float* Wih_b = (const float*)d_in[7];
    const float* Whh_b = (const float*)d_in[8];
    const float* bih_b = (const float*)d_in[9];
    const float* bhh_b = (const float*)d_in[10];
    const float* W1    = (const float*)d_in[11];
    const float* b1    = (const float*)d_in[12];
    const float* W2    = (const float*)d_in[13];
    const float* b2    = (const float*)d_in[14];
    float* out = (float*)d_out;

    uintptr_t ws = (uintptr_t)d_ws;
    bf16_t*   Wf   = (bf16_t*)(ws);                    // 1,572,864
    float*    bias = (float*)(ws + 1572864);           // 8,192
    bf16_t*   xBf  = (bf16_t*)(ws + 1581056);          // 39,321,600
    bf16_t*   hAb  = (bf16_t*)(ws + 40902656);         // 5,242,880
    bf16_t*   hBb  = (bf16_t*)(ws + 46145536);         // 5,242,880
    bf16_t*   hfin = (bf16_t*)(ws + 51388416);         // 5,242,880
    float*    W1T  = (float*)(ws + 56631296);          // 655,360
    unsigned* bar  = (unsigned*)(ws + 57286656);       // 4,096

    hipMemsetAsync((void*)bar, 0, 4096, stream);

    prep_weights<<<(2 * G4 * 384 + 255) / 256, 256, 0, stream>>>(
        Wih_f, Whh_f, bih_f, bhh_f, Wih_b, Whh_b, bih_b, bhh_b, Wf, bias);
    prep_x<<<(NBGRP * TSEQ * SLABX + 255) / 256, 256, 0, stream>>>(x, xBf);
    prep_state<<<(2 * NBGRP * SLABH + 255) / 256, 256, 0, stream>>>(h0, hAb);
    prep_w1t<<<(2560 * 64 + 255) / 256, 256, 0, stream>>>(W1, W1T);

    lstm_persist<<<256, 512, 0, stream>>>(Wf, bias, xBf, c0, hAb, hBb, hfin, bar);
    head_kernel<<<BATCH, 256, 0, stream>>>(hfin, W1T, b1, W2, b2, out);
}

// Round 10
// 831.962 us; speedup vs baseline: 1.7145x; 1.1856x over previous
//
#include <hip/hip_runtime.h>

typedef __bf16 bf16_t;
typedef __bf16 bf16x8 __attribute__((ext_vector_type(8)));
typedef float f32x4 __attribute__((ext_vector_type(4)));

#define TSEQ 30
#define ISZ  100
#define HSZ  256
#define NB   5120        // LSTM batch
#define BATCH 512
#define G4   1024        // 4*H
#define TILE 320         // batch cols per block
#define NBGRP 16
#define CH   10240       // elements per K=32 chunk panel: 20 nblk * 512
#define SLABX (4 * CH)   // x slab per (bgrp,t): K=128
#define SLABH (8 * CH)   // h slab per (dir,bgrp): K=256

__device__ __forceinline__ float fsig(float x)  { return 1.0f / (1.0f + __expf(-x)); }
__device__ __forceinline__ float ftanh(float x) { return 2.0f / (1.0f + __expf(-2.0f * x)) - 1.0f; }

// ---- prep: weights -> MFMA-fragment layout, fold biases ------------------
// Wf[d][mf 0..63][ks 0..11][lane 0..63][e 0..7]; gate row r = h*4+gate
__global__ void prep_weights(const float* __restrict__ Wih_f, const float* __restrict__ Whh_f,
                             const float* __restrict__ bih_f, const float* __restrict__ bhh_f,
                             const float* __restrict__ Wih_b, const float* __restrict__ Whh_b,
                             const float* __restrict__ bih_b, const float* __restrict__ bhh_b,
                             bf16_t* __restrict__ Wf, float* __restrict__ bias)
{
    int idx = blockIdx.x * 256 + threadIdx.x;          // over 2*1024*384
    if (idx >= 2 * G4 * 384) return;
    int d = idx / (G4 * 384);
    int r = (idx / 384) % G4;
    int k = idx % 384;
    int h = r >> 2, gate = r & 3;
    int grow = gate * HSZ + h;
    const float* Wih = d ? Wih_b : Wih_f;
    const float* Whh = d ? Whh_b : Whh_f;
    float v;
    if (k < ISZ)       v = Wih[grow * ISZ + k];
    else if (k < 128)  v = 0.0f;
    else               v = Whh[grow * HSZ + (k - 128)];
    int mf = r >> 4, lr = r & 15;
    int ks = k >> 5, lq = (k >> 3) & 3, e = k & 7;
    size_t o = ((((size_t)d * 64 + mf) * 12 + ks) * 64 + lq * 16 + lr) * 8 + e;
    Wf[o] = (bf16_t)v;
    if (k == 0) {
        const float* bih = d ? bih_b : bih_f;
        const float* bhh = d ? bhh_b : bhh_f;
        bias[d * G4 + r] = bih[grow] + bhh[grow];
    }
}

// ---- prep: x -> fragment layout, chunk-contiguous ------------------------
// xBf[bgrp][t][ks 0..3][nblk 0..19][lane][e]
__global__ void prep_x(const float* __restrict__ x, bf16_t* __restrict__ xBf)
{
    int idx = blockIdx.x * 256 + threadIdx.x;          // over 16*30*4*20*512
    if (idx >= NBGRP * TSEQ * SLABX) return;
    int e    = idx & 7;
    int lane = (idx >> 3) & 63;
    int i2   = idx >> 9;
    int nblk = i2 % 20; i2 /= 20;
    int ks   = i2 & 3;  i2 >>= 2;
    int t    = i2 % TSEQ;
    int bgrp = i2 / TSEQ;
    int n = bgrp * TILE + nblk * 16 + (lane & 15);
    int k = ks * 32 + (lane >> 4) * 8 + e;
    float v = (k < ISZ) ? x[(size_t)n * (TSEQ * ISZ) + t * ISZ + k] : 0.0f;
    xBf[idx] = (bf16_t)v;
}

// ---- prep: h0 -> fragment layout ping buffer -----------------------------
// hA[dir][bgrp][ksh 0..7][nblk 0..19][lane][e]
__global__ void prep_state(const float* __restrict__ h0, bf16_t* __restrict__ hA)
{
    int idx = blockIdx.x * 256 + threadIdx.x;          // over 2*16*8*20*512
    if (idx >= 2 * NBGRP * SLABH) return;
    int e    = idx & 7;
    int lane = (idx >> 3) & 63;
    int i2   = idx >> 9;
    int nblk = i2 % 20; i2 /= 20;
    int ksh  = i2 & 7;  i2 >>= 3;
    int bgrp = i2 & 15;
    int dir  = i2 >> 4;
    int col = bgrp * TILE + nblk * 16 + (lane & 15);
    int hid = ksh * 32 + (lane >> 4) * 8 + e;
    hA[idx] = (bf16_t)h0[((size_t)dir * NB + col) * HSZ + hid];
}

// ---- prep: c0 -> per-thread-contiguous layout ----------------------------
// cws[(bid*512+tid)*20 + nf*4 + m]
__global__ void prep_c(const float* __restrict__ c0, float* __restrict__ cws)
{
    int idx = blockIdx.x * 256 + threadIdx.x;          // over 256*512*20
    if (idx >= 256 * 512 * 20) return;
    int m   = idx & 3;
    int nf  = (idx >> 2) % 5;
    int tid = (idx / 20) & 511;
    int bid = idx / (20 * 512);
    int msub = bid >> 5, dir = (bid >> 4) & 1, bgrp = bid & 15;
    int lane = tid & 63, mw = (tid >> 6) >> 2, nw = (tid >> 6) & 3;
    int lr = lane & 15, lq = lane >> 4;
    int col = bgrp * TILE + nw * 80 + nf * 16 + lr;
    int hid = msub * 32 + mw * 16 + m * 4 + lq;
    cws[idx] = c0[((size_t)dir * NB + col) * HSZ + hid];
}

// ---- prep: transpose W1 for coalesced head ------------------------------
__global__ void prep_w1t(const float* __restrict__ W1, float* __restrict__ W1T)
{
    int idx = blockIdx.x * 256 + threadIdx.x;          // over 2560*64
    if (idx >= 2560 * 64) return;
    int k = idx / 64, j = idx % 64;
    W1T[k * 64 + j] = W1[j * 2560 + k];
}

// ---- one LSTM step: M-split + W-in-LDS, launched 30x ---------------------
// 256 blocks x 512 thr. bid = msub*32 + dir*16 + bgrp; bid->XCD stable across
// launches so each block's W slice / c slice / h slab stay L2-local.
// r9 lesson: the in-kernel device barrier (agent fences + atomic spin) was the
// ~25µs/step wall; kernel boundaries give the same coherence for ~2-4µs.
__global__ __launch_bounds__(512, 1)
void lstm_step(const bf16_t* __restrict__ Wf, const float* __restrict__ bias,
               const bf16_t* __restrict__ xBf, const bf16_t* __restrict__ hs,
               bf16_t* __restrict__ hw, float* __restrict__ cws,
               bf16_t* __restrict__ hfin, int t)
{
    __shared__ __align__(16) bf16_t wL[8 * 12 * 512];  // 96KB W slice
    __shared__ __align__(16) bf16_t chk[3][CH];        // 3 x 20KB act chunks

    const int bid  = blockIdx.x;
    const int msub = bid >> 5;
    const int dir  = (bid >> 4) & 1;
    const int bgrp = bid & 15;
    const int tid  = threadIdx.x;
    const int lane = tid & 63;
    const int mw   = (tid >> 6) >> 2;                  // 0..1
    const int nw   = (tid >> 6) & 3;                   // 0..3
    const int lr   = lane & 15;
    const int lq   = lane >> 4;

    const int tx = dir ? (TSEQ - 1 - t) : t;
    const bf16_t* xs  = xBf + (size_t)(bgrp * TSEQ + tx) * SLABX;
    const bf16_t* hsl = hs + (size_t)(dir * NBGRP + bgrp) * SLABH;

    // --- upfront (all loads overlap): W slice, c, bias, chunks 0+1 ---
    {
        const uint4* wsrc = (const uint4*)(Wf + ((size_t)dir * 64 + msub * 8) * 12 * 512);
        uint4* wdst = (uint4*)wL;
        for (int i = tid; i < 6144; i += 512) wdst[i] = wsrc[i];
    }
    float* cp = cws + ((size_t)bid * 512 + tid) * 20;
    f32x4 c4[5];
#pragma unroll
    for (int nf = 0; nf < 5; ++nf) c4[nf] = *(const f32x4*)(cp + nf * 4);
    float4 bq[4];
#pragma unroll
    for (int m = 0; m < 4; ++m)
        bq[m] = *(const float4*)(bias + dir * G4 + (msub * 32 + mw * 16 + m * 4 + lq) * 4);
    {
        const uint4* s0 = (const uint4*)xs;
        const uint4* s1 = (const uint4*)(xs + CH);
        uint4* d0 = (uint4*)chk[0];
        uint4* d1 = (uint4*)chk[1];
        for (int i = tid; i < 1280; i += 512) { d0[i] = s0[i]; d1[i] = s1[i]; }
    }
    __syncthreads();

    // --- 12 K=32 chunks, 3-buffer / 2-deep staging pipeline ---
    f32x4 acc[4][5] = {};
#pragma unroll
    for (int c = 0; c < 12; ++c) {
        if (c < 10) {                                  // stage chunk c+2
            const uint4* src = (c + 2 < 4)
                ? (const uint4*)(xs  + (size_t)(c + 2) * CH)
                : (const uint4*)(hsl + (size_t)(c - 2) * CH);
            uint4* dst = (uint4*)chk[(c + 2) % 3];
            for (int i = tid; i < 1280; i += 512) dst[i] = src[i];
        }
        bf16x8 b[5];
#pragma unroll
        for (int nf = 0; nf < 5; ++nf)
            b[nf] = *(const bf16x8*)(chk[c % 3] + (nw * 5 + nf) * 512 + lane * 8);
        bf16x8 a[4];
#pragma unroll
        for (int m = 0; m < 4; ++m)
            a[m] = *(const bf16x8*)(wL + ((mw * 4 + m) * 12 + c) * 512 + lane * 8);
#pragma unroll
        for (int m = 0; m < 4; ++m)
#pragma unroll
            for (int nf = 0; nf < 5; ++nf)
                acc[m][nf] = __builtin_amdgcn_mfma_f32_16x16x32_bf16(a[m], b[nf], acc[m][nf], 0, 0, 0);
        __syncthreads();
    }

    // --- gates + state; h -> hw fragment layout (or hfin plain at t=29) ---
    bf16_t* hwsl = hw + (size_t)(dir * NBGRP + bgrp) * SLABH;
    const int lastt = (t == TSEQ - 1);
#pragma unroll
    for (int m = 0; m < 4; ++m) {
        float4 bb = bq[m];
#pragma unroll
        for (int nf = 0; nf < 5; ++nf) {
            f32x4 g = acc[m][nf];
            float gi = fsig(g[0] + bb.x);
            float gf = fsig(g[1] + bb.y);
            float gz = ftanh(g[2] + bb.z);
            float go = fsig(g[3] + bb.w);
            float cn = gf * c4[nf][m] + gi * gz;
            c4[nf][m] = cn;
            float hn = go * ftanh(cn);
            if (!lastt) {
                int hl = mw * 16 + m * 4 + lq;         // local hid within msub's 32
                int off = (msub * 20 + nw * 5 + nf) * 512 + ((hl >> 3) * 16 + lr) * 8 + (hl & 7);
                hwsl[off] = (bf16_t)hn;
            } else {
                int col = bgrp * TILE + nw * 80 + nf * 16 + lr;
                int hid = msub * 32 + mw * 16 + m * 4 + lq;
                hfin[((size_t)dir * NB + col) * HSZ + hid] = (bf16_t)hn;
            }
        }
    }
    if (!lastt) {
#pragma unroll
        for (int nf = 0; nf < 5; ++nf) *(f32x4*)(cp + nf * 4) = c4[nf];
    }
}

// ---- head: x_fea assembly + Linear(2560,64) + Linear(64,5) + softmax ----
__global__ __launch_bounds__(256)
void head_kernel(const bf16_t* __restrict__ hfin, const float* __restrict__ W1T,
                 const float* __restrict__ b1, const float* __restrict__ W2,
                 const float* __restrict__ b2, float* __restrict__ out)
{
    __shared__ float flat_s[2560];
    __shared__ float partial[4][64];
    __shared__ float zs[64];
    __shared__ float ls[5];
    __shared__ float es[5];
    int b = blockIdx.x, tid = threadIdx.x;
    const bf16_t* hF = hfin;
    const bf16_t* hB = hfin + (size_t)NB * HSZ;
    float* xfea = out + BATCH * 5 + (size_t)b * 2560;

    for (int j = tid; j < 2560; j += 256) {
        int s = j >> 8, c = j & 255;
        int n = b * 10 + s;
        float v = (c < 128) ? (float)hF[(size_t)n * HSZ + c] : (float)hB[(size_t)n * HSZ + c];
        flat_s[j] = v;
        xfea[j] = v;
    }
    __syncthreads();
    int j = tid & 63, q = tid >> 6;
    float sum = 0.0f;
    for (int k = q * 640; k < (q + 1) * 640; ++k) sum += flat_s[k] * W1T[k * 64 + j];
    partial[q][j] = sum;
    __syncthreads();
    if (tid < 64) zs[tid] = partial[0][tid] + partial[1][tid] + partial[2][tid] + partial[3][tid] + b1[tid];
    __syncthreads();
    if (tid < 5) {
        float l = b2[tid];
        for (int k = 0; k < 64; ++k) l += zs[k] * W2[tid * 64 + k];
        ls[tid] = l;
    }
    __syncthreads();
    if (tid < 5) {
        float m = ls[0];
        for (int k = 1; k < 5; ++k) m = fmaxf(m, ls[k]);
        es[tid] = __expf(ls[tid] - m);
    }
    __syncthreads();
    if (tid < 5) {
        float s5 = es[0] + es[1] + es[2] + es[3] + es[4];
        out[b * 5 + tid] = es[tid] / s5;
    }
}

extern "C" void kernel_launch(void* const* d_in, const int* in_sizes, int n_in,
                              void* d_out, int out_size, void* d_ws, size_t ws_size,
                              hipStream_t stream) {
    const float* x     = (const float*)d_in[0];
    const float* h0    = (const float*)d_in[1];
    const float* c0    = (const float*)d_in[2];
    const float* Wih_f = (const float*)d_in[3];
    const float* Whh_f = (const float*)d_in[4];
    const float* bih_f = (const float*)d_in[5];
    const float* bhh_f = (const float*)d_in[6];
    const float* Wih_b = (const float*)d_in[7];
    const float* Whh_b = (const float*)d_in[8];
    const float* bih_b = (const float*)d_in[9];
    const float* bhh_b = (const float*)d_in[10];
    const float* W1    = (const float*)d_in[11];
    const float* b1    = (const float*)d_in[12];
    const float* W2    = (const float*)d_in[13];
    const float* b2    = (const float*)d_in[14];
    float* out = (float*)d_out;

    uintptr_t ws = (uintptr_t)d_ws;
    bf16_t*   Wf   = (bf16_t*)(ws);                    // 1,572,864
    float*    bias = (float*)(ws + 1572864);           // 8,192
    bf16_t*   xBf  = (bf16_t*)(ws + 1581056);          // 39,321,600
    bf16_t*   hAb  = (bf16_t*)(ws + 40902656);         // 5,242,880
    bf16_t*   hBb  = (bf16_t*)(ws + 46145536);         // 5,242,880
    bf16_t*   hfin = (bf16_t*)(ws + 51388416);         // 5,242,880
    float*    W1T  = (float*)(ws + 56631296);          // 655,360
    float*    cws  = (float*)(ws + 57286656);          // 10,485,760

    prep_weights<<<(2 * G4 * 384 + 255) / 256, 256, 0, stream>>>(
        Wih_f, Whh_f, bih_f, bhh_f, Wih_b, Whh_b, bih_b, bhh_b, Wf, bias);
    prep_x<<<(NBGRP * TSEQ * SLABX + 255) / 256, 256, 0, stream>>>(x, xBf);
    prep_state<<<(2 * NBGRP * SLABH + 255) / 256, 256, 0, stream>>>(h0, hAb);
    prep_c<<<(256 * 512 * 20 + 255) / 256, 256, 0, stream>>>(c0, cws);
    prep_w1t<<<(2560 * 64 + 255) / 256, 256, 0, stream>>>(W1, W1T);

    for (int t = 0; t < TSEQ; ++t) {
        bf16_t* hR = (t & 1) ? hBb : hAb;
        bf16_t* hW = (t & 1) ? hAb : hBb;
        lstm_step<<<256, 512, 0, stream>>>(Wf, bias, xBf, hR, hW, cws, hfin, t);
    }
    head_kernel<<<BATCH, 256, 0, stream>>>(hfin, W1T, b1, W2, b2, out);
}